// Round 32
// baseline (37.902 us; speedup 1.0000x reference)
//
#include <hip/hip_runtime.h>
#include <hip/hip_fp8.h>

// R32 = R29/R31 + per-wave DOUBLE-BUFFERED M/Dt, 1-stage software pipeline:
// iter n writes group n into buf[n&1], MFMAs group n-1 from buf[1-(n&1)].
// Breaks the per-group write->lgkmcnt->read->lgkmcnt->MFMA serial chain
// (~370cy/group = the observed 30us main kernel; R30/R31 proved occupancy
// and load-prefetch don't touch it). Buffer parity is compile-time via the
// unrolled A/B loop. LDS 45KB -> 3 blocks/CU (R22: 3 vs 4 neutral), grid 768.
// Search / fp8 layout / reduce tree byte-identical to R29.

#define NG 64
#define NCOMP 6
#define NPART (NG * NCOMP)      // 384
#define RED1_BLOCKS 64
#define MFMA_BLOCKS 768         // 3 blocks/CU at 45KB LDS
#define WPB 4
#define MROWB 80                // 64 + 16 pad bytes; 16B-aligned rows
#define DROWB 80
#define DTROWS 6                // rows 0..5 real; C cols 6..15 discarded

typedef unsigned char  u8_t;
typedef unsigned int   u32_t;
typedef __attribute__((ext_vector_type(2))) long long long2_t;
typedef __attribute__((ext_vector_type(4))) float f32x4;

__device__ __forceinline__ int eperm(int e) {
    return (((e >> 3) & 3) << 4) | (((e >> 5) & 1) << 3) | (e & 7);
}

__device__ __forceinline__ u8_t f2fp8(float f) {
    return (u8_t)__hip_cvt_float_to_fp8(f, __HIP_SATFINITE, __HIP_E4M3);
}

__device__ __forceinline__ void lds_add(float* p, float v) {
    __hip_atomic_fetch_add(p, v, __ATOMIC_RELAXED, __HIP_MEMORY_SCOPE_WORKGROUP);
}

// Estimate-and-verify: g = max{g : Bs[g] <= a}. Bs[0]=0, Bs[64]=N sentinel.
__device__ __forceinline__ int gsearch(const int* Bs, int a, float rcpN) {
    int g = (int)((float)a * rcpN);
    g = g > 63 ? 63 : g;
    while (Bs[g] > a) --g;          // fires for ~4% of lanes
    while (Bs[g + 1] <= a) ++g;     // fires for ~4% of lanes
    return g;
}

// ---------------- MFMA main kernel (fp8, dbuf, 1-stage pipeline) ----------------
__global__ __launch_bounds__(256) void virial_mfma(
    const float* __restrict__ disp, const float* __restrict__ edge_w,
    const int* __restrict__ edge_index, const int* __restrict__ batch,
    float* __restrict__ partials, int E, int N, float rcpN)
{
    __shared__ u8_t Msh0[WPB][NG * MROWB];      // 20480 B  (buf0; f32 stage after loop)
    __shared__ u8_t Msh1[WPB][NG * MROWB];      // 20480 B  (buf1)
    __shared__ u8_t Dsh0[WPB][DTROWS * DROWB];  //  1920 B
    __shared__ u8_t Dsh1[WPB][DTROWS * DROWB];  //  1920 B
    __shared__ int  Bs[65];                     //   260 B   (~45KB total)

    const int lane = threadIdx.x & 63;
    const int wave = threadIdx.x >> 6;
    u8_t* Mw0 = Msh0[wave];
    u8_t* Mw1 = Msh1[wave];
    u8_t* Dw0 = Dsh0[wave];
    u8_t* Dw1 = Dsh1[wave];

    // Fused bounds table: Bs[g] = lower_bound(batch, g) (batch sorted, L2-hot)
    if (threadIdx.x < 65) {
        int g = threadIdx.x;
        int lo = 0, len = N;
        while (len > 0) {
            int half = len >> 1;
            int mid  = lo + half;
            if (batch[mid] < g) { lo = mid + 1; len -= half + 1; }
            else                { len = half; }
        }
        Bs[g] = lo;    // g=64 -> N (sentinel)
    }
    {   // zero both per-wave buffers (same-wave DS ops are in order)
        u32_t* p0 = (u32_t*)Mw0;
        u32_t* p1 = (u32_t*)Mw1;
        for (int i = lane; i < NG * MROWB / 4; i += 64) { p0[i] = 0u; p1[i] = 0u; }
        u32_t* q0 = (u32_t*)Dw0;
        u32_t* q1 = (u32_t*)Dw1;
        for (int i = lane; i < DTROWS * DROWB / 4; i += 64) { q0[i] = 0u; q1[i] = 0u; }
    }
    __syncthreads();   // Bs ready

    f32x4 acc0 = {0,0,0,0}, acc1 = {0,0,0,0}, acc2 = {0,0,0,0}, acc3 = {0,0,0,0};
    const int ngroups = (E + 63) >> 6;
    const int gstride = (int)gridDim.x * WPB;
    const int c_l  = lane & 15;
    const int k4   = lane >> 4;
    const int mcol = eperm(lane);                            // storage column
    const int drow = (c_l < DTROWS) ? c_l : (DTROWS - 1);    // junk -> discarded C cols

#define LOADG(G, W, X, Y, Z, S, T) do {                                     \
        int e_  = (G) * 64 + lane;                                          \
        int ec_ = e_ < E ? e_ : E - 1;                                      \
        W = (e_ < E) ? edge_w[ec_] : 0.f;  /* w=0 kills clamped tail */     \
        X = disp[ec_ * 3 + 0];                                              \
        Y = disp[ec_ * 3 + 1];                                              \
        Z = disp[ec_ * 3 + 2];                                              \
        S = edge_index[ec_];                                                \
        T = edge_index[E + ec_];                                            \
    } while (0)

    // write phase only: search + M one-hot + Dt (no fragment reads)
#define WRITEG(MW, DW, PG0, PG1, W, X, Y, Z, S, T) do {                     \
        const int g0_ = gsearch(Bs, S, rcpN);                               \
        const int g1_ = gsearch(Bs, T, rcpN);                               \
        MW[PG0 * MROWB + mcol] = 0;                                         \
        MW[PG1 * MROWB + mcol] = 0;                                         \
        MW[g0_ * MROWB + mcol] = 0x38u;                                     \
        MW[g1_ * MROWB + mcol] = (g1_ == g0_) ? 0x40u : 0x38u;              \
        PG0 = g0_; PG1 = g1_;                                               \
        float cw_ = -2.f * W;                                               \
        DW[0 * DROWB + mcol] = f2fp8(cw_ * X * X);                          \
        DW[1 * DROWB + mcol] = f2fp8(cw_ * X * Y);                          \
        DW[2 * DROWB + mcol] = f2fp8(cw_ * X * Z);                          \
        DW[3 * DROWB + mcol] = f2fp8(cw_ * Y * Y);                          \
        DW[4 * DROWB + mcol] = f2fp8(cw_ * Y * Z);                          \
        DW[5 * DROWB + mcol] = f2fp8(cw_ * Z * Z);                          \
    } while (0)

    // fragment reads + 8 MFMA from one buffer (writes to it are >=1 iter old)
#define MFMAG(MW, DW) do {                                                  \
        long2_t bf_ = *(const long2_t*)&DW[drow * DROWB + k4 * 16];         \
        long2_t a0_ = *(const long2_t*)&MW[( 0 + c_l) * MROWB + k4 * 16];   \
        long2_t a1_ = *(const long2_t*)&MW[(16 + c_l) * MROWB + k4 * 16];   \
        long2_t a2_ = *(const long2_t*)&MW[(32 + c_l) * MROWB + k4 * 16];   \
        long2_t a3_ = *(const long2_t*)&MW[(48 + c_l) * MROWB + k4 * 16];   \
        acc0 = __builtin_amdgcn_mfma_f32_16x16x32_fp8_fp8(a0_[0], bf_[0], acc0, 0, 0, 0); \
        acc1 = __builtin_amdgcn_mfma_f32_16x16x32_fp8_fp8(a1_[0], bf_[0], acc1, 0, 0, 0); \
        acc2 = __builtin_amdgcn_mfma_f32_16x16x32_fp8_fp8(a2_[0], bf_[0], acc2, 0, 0, 0); \
        acc3 = __builtin_amdgcn_mfma_f32_16x16x32_fp8_fp8(a3_[0], bf_[0], acc3, 0, 0, 0); \
        acc0 = __builtin_amdgcn_mfma_f32_16x16x32_fp8_fp8(a0_[1], bf_[1], acc0, 0, 0, 0); \
        acc1 = __builtin_amdgcn_mfma_f32_16x16x32_fp8_fp8(a1_[1], bf_[1], acc1, 0, 0, 0); \
        acc2 = __builtin_amdgcn_mfma_f32_16x16x32_fp8_fp8(a2_[1], bf_[1], acc2, 0, 0, 0); \
        acc3 = __builtin_amdgcn_mfma_f32_16x16x32_fp8_fp8(a3_[1], bf_[1], acc3, 0, 0, 0); \
    } while (0)

    int grp = (int)blockIdx.x * WPB + wave;

    // 2-deep load prologue (A <- grp, B <- grp+gs)
    float wA = 0.f, xA = 0.f, yA = 0.f, zA = 0.f;
    int   sA = 0, tA = 0;
    float wB = 0.f, xB = 0.f, yB = 0.f, zB = 0.f;
    int   sB = 0, tB = 0;
    if (grp < ngroups)           LOADG(grp,           wA, xA, yA, zA, sA, tA);
    if (grp + gstride < ngroups) LOADG(grp + gstride, wB, xB, yB, zB, sB, tB);

    int pg0a = 0, pg1a = 0, pg0b = 0, pg1b = 0;
    bool first = true;
    bool lastA = true;

    while (grp < ngroups) {
        // A-iteration: write buf0; MFMA buf1 (previous B-group)
        WRITEG(Mw0, Dw0, pg0a, pg1a, wA, xA, yA, zA, sA, tA);
        if (grp + 2 * gstride < ngroups)
            LOADG(grp + 2 * gstride, wA, xA, yA, zA, sA, tA);
        if (!first) MFMAG(Mw1, Dw1);
        first = false;
        lastA = true;
        grp += gstride;
        if (grp >= ngroups) break;

        // B-iteration: write buf1; MFMA buf0 (previous A-group)
        WRITEG(Mw1, Dw1, pg0b, pg1b, wB, xB, yB, zB, sB, tB);
        if (grp + 2 * gstride < ngroups)
            LOADG(grp + 2 * gstride, wB, xB, yB, zB, sB, tB);
        MFMAG(Mw0, Dw0);
        lastA = false;
        grp += gstride;
    }
    // drain: MFMA the last-written buffer
    if (!first) {
        if (lastA) MFMAG(Mw0, Dw0);
        else       MFMAG(Mw1, Dw1);
    }
#undef LOADG
#undef WRITEG
#undef MFMAG

    // C/D layout: col=lane&15, row=(lane>>4)*4+reg (dtype-independent).
    // Stage per-wave f32 partial into this wave's (now dead) Msh0 region.
    __syncthreads();
    float* Ow = (float*)Mw0;   // 5120 B >= 1536 B needed
    if (c_l < NCOMP) {
#pragma unroll
        for (int r = 0; r < 4; ++r) {
            Ow[( 0 + k4 * 4 + r) * NCOMP + c_l] = acc0[r];
            Ow[(16 + k4 * 4 + r) * NCOMP + c_l] = acc1[r];
            Ow[(32 + k4 * 4 + r) * NCOMP + c_l] = acc2[r];
            Ow[(48 + k4 * 4 + r) * NCOMP + c_l] = acc3[r];
        }
    }
    __syncthreads();
    for (int i = threadIdx.x; i < NPART; i += blockDim.x) {
        float s = ((const float*)Msh0[0])[i] + ((const float*)Msh0[1])[i]
                + ((const float*)Msh0[2])[i] + ((const float*)Msh0[3])[i];
        partials[(size_t)blockIdx.x * NPART + i] = s;
    }
}

// ---------------- reductions (atomic-free; R22-verified) ----------------
__global__ __launch_bounds__(NPART) void reduce1_kernel(
    const float* __restrict__ partials, float* __restrict__ partials2, int nblk)
{
    int i = threadIdx.x, j = blockIdx.x;
    float s = 0.f;
    for (int b = j; b < nblk; b += RED1_BLOCKS)
        s += partials[(size_t)b * NPART + i];
    partials2[(size_t)j * NPART + i] = s;
}

__global__ __launch_bounds__(NPART) void reduce2_kernel(
    const float* __restrict__ partials2, float* __restrict__ dst)  // dst: 64*9
{
    int i = threadIdx.x;
    float s = 0.f;
#pragma unroll
    for (int j = 0; j < RED1_BLOCKS; ++j)
        s += partials2[(size_t)j * NPART + i];
    int g = i / NCOMP, c = i % NCOMP;
    int r   = (c < 3) ? 0 : ((c < 5) ? 1 : 2);
    int col = (c < 3) ? c : ((c < 5) ? c - 2 : 2);
    dst[g * 9 + r * 3 + col] = s;
    if (r != col) dst[g * 9 + col * 3 + r] = s;
}

// ---------------- fallback (tiny ws): LDS-atomic path ----------------
__global__ void zero_out_kernel(float* __restrict__ out, int n) {
    int i = blockIdx.x * blockDim.x + threadIdx.x;
    if (i < n) out[i] = 0.f;
}

__global__ __launch_bounds__(256) void virial_atomic(
    const float* __restrict__ disp, const float* __restrict__ edge_w,
    const int* __restrict__ edge_index, const int* __restrict__ batch,
    float* __restrict__ out, int E)
{
    __shared__ float acc[NG * 7];
    for (int i = threadIdx.x; i < NG * 7; i += blockDim.x) acc[i] = 0.f;
    __syncthreads();
    int tid = blockIdx.x * blockDim.x + threadIdx.x;
    int stride = gridDim.x * blockDim.x;
    for (int e = tid; e < E; e += stride) {
        float d0 = disp[e*3], d1 = disp[e*3+1], d2 = disp[e*3+2];
        float c = -2.f * edge_w[e];
        int g0 = batch[edge_index[e]], g1 = batch[edge_index[E + e]];
        float v[6] = {c*d0*d0, c*d0*d1, c*d0*d2, c*d1*d1, c*d1*d2, c*d2*d2};
#pragma unroll
        for (int k = 0; k < 6; ++k) {
            lds_add(&acc[g0*7+k], v[k]);
            lds_add(&acc[g1*7+k], v[k]);
        }
    }
    __syncthreads();
    for (int i = threadIdx.x; i < NG * 9; i += blockDim.x) {
        int g = i / 9, ij = i % 9, r = ij / 3, cc = ij % 3;
        int lo = r < cc ? r : cc, hi = r < cc ? cc : r;
        int comp = (lo == 0) ? hi : ((lo == 1) ? 2 + hi : 5);
        __hip_atomic_fetch_add(&out[i], acc[g*7+comp], __ATOMIC_RELAXED, __HIP_MEMORY_SCOPE_AGENT);
    }
}

extern "C" void kernel_launch(void* const* d_in, const int* in_sizes, int n_in,
                              void* d_out, int out_size, void* d_ws, size_t ws_size,
                              hipStream_t stream) {
    const float* disp       = (const float*)d_in[0];
    const float* edge_w     = (const float*)d_in[1];
    const int*   edge_index = (const int*)d_in[2];
    const int*   batch      = (const int*)d_in[3];
    float*       out        = (float*)d_out;
    const int E = in_sizes[1];
    const int N = in_sizes[3];
    const float rcpN = (float)NG / (float)N;

    const size_t need = (size_t)(MFMA_BLOCKS + RED1_BLOCKS) * NPART * sizeof(float);

    if (ws_size >= need) {
        float* pm = (float*)d_ws;                         // [MFMA_BLOCKS][NPART]
        float* p2 = pm + (size_t)MFMA_BLOCKS * NPART;     // [RED1_BLOCKS][NPART]

        virial_mfma<<<MFMA_BLOCKS, 256, 0, stream>>>(disp, edge_w, edge_index,
                                                     batch, pm, E, N, rcpN);
        reduce1_kernel<<<RED1_BLOCKS, NPART, 0, stream>>>(pm, p2, MFMA_BLOCKS);
        reduce2_kernel<<<1, NPART, 0, stream>>>(p2, out);
    } else {
        zero_out_kernel<<<1, 256, 0, stream>>>(out, NG * 9);
        virial_atomic<<<2048, 256, 0, stream>>>(disp, edge_w, edge_index, batch, out, E);
    }
}